// Round 19
// baseline (245.702 us; speedup 1.0000x reference)
//
#include <hip/hip_runtime.h>
#include <hip/hip_bf16.h>
#include <math.h>

// CrossPairMemory round 19: r18 (244.6us verified best) + ONE change:
// pair_final gets gemm224-style 2-phase double-buffering (stage kt+1 before
// computing kt; LDS 64KB, 2 blocks/CU). Everything else r18-identical.

#define B_SZ  4096
#define NPAIR 28
#define PDIM  128
#define MDIM  256
#define NSLOT 64
#define DALL  3584
#define DCAT  7168
#define KS2   32
#define KCH2  224   // DCAT / KS2

typedef __hip_bfloat16 bf16;
typedef __attribute__((ext_vector_type(8))) short bf16x8;
typedef __attribute__((ext_vector_type(4))) short short4v;
typedef __attribute__((ext_vector_type(4))) float f32x4;

#define BARRIER() asm volatile("s_barrier" ::: "memory")
#define LGKM0()   asm volatile("s_waitcnt lgkmcnt(0)" ::: "memory")
#define VMCNT4()  asm volatile("s_waitcnt vmcnt(4)" ::: "memory")
#define VMCNT3()  asm volatile("s_waitcnt vmcnt(3)" ::: "memory")
#define VMCNT0()  asm volatile("s_waitcnt vmcnt(0)" ::: "memory")

__device__ __forceinline__ void async_copy16(void* lds, const void* g) {
  __builtin_amdgcn_global_load_lds((__attribute__((address_space(1))) void*)g,
                                   (__attribute__((address_space(3))) void*)lds,
                                   16, 0, 0);
}

// ============== 256x224x64 1-barrier GEMM: A dbuf + B tribuf (r18) =========
__global__ __launch_bounds__(512, 2)
void gemm224(const bf16* __restrict__ A, const bf16* __restrict__ Bt,
             bf16* __restrict__ Cout, const float* __restrict__ bias) {
  __shared__ __align__(16) char smem[151552];   // 64KB A + 84KB B
  const int tid = threadIdx.x;
  const int wid = tid >> 6, lane = tid & 63;
  const int lr = lane & 15, lk = lane >> 4;
  const int wm = wid >> 1, wn = wid & 1;
  const int swz = ((int)blockIdx.x & 7) * 32 + ((int)blockIdx.x >> 3);
  const int bx = swz & 15, by = swz >> 4;
  const int col0 = bx * 224, row0 = by * 256;

  char* sA = smem;            // 2 x 32768
  char* sB = smem + 65536;    // 3 x 28672

  const int srow = tid >> 3;
  const int sg = (tid & 7) ^ (srow & 7);
  const bf16* aStage = A + (long)(row0 + srow) * DALL + sg * 8;
  const bf16* bStage = Bt + (long)(col0 + srow) * DALL + sg * 8;
  const int wOff = wid << 10;
  const int loWave = (wid < 4);

  const int NT = DALL >> 6;  // 56

  const int sx = lr & 7;
  const int arowb = wm * 64 + lr;
  const int browb = wn * 112 + lr;

  f32x4 acc[4][7];
  const f32x4 zero = {0.f, 0.f, 0.f, 0.f};
#pragma unroll
  for (int m = 0; m < 4; ++m)
#pragma unroll
    for (int n = 0; n < 7; ++n) acc[m][n] = zero;

#pragma unroll
  for (int i = 0; i < 4; ++i)
    async_copy16(sA + i * 8192 + wOff, aStage + (long)i * 64 * DALL);
#pragma unroll
  for (int i = 0; i < 3; ++i)
    async_copy16(sB + i * 8192 + wOff, bStage + (long)i * 64 * DALL);
  if (loWave)
    async_copy16(sB + 24576 + wOff, bStage + (long)192 * DALL);
#pragma unroll
  for (int i = 0; i < 3; ++i)
    async_copy16(sB + 28672 + i * 8192 + wOff, bStage + (long)i * 64 * DALL + 64);
  if (loWave)
    async_copy16(sB + 28672 + 24576 + wOff, bStage + (long)192 * DALL + 64);
  if (loWave) { VMCNT4(); } else { VMCNT3(); }
  BARRIER();

  bf16x8 af[4][2], bf[7][2];

  for (int t = 0; t < NT; ++t) {
    char* cA = sA + (t & 1) * 32768;
    char* cB = sB + (t % 3) * 28672;

#pragma unroll
    for (int m = 0; m < 4; ++m)
#pragma unroll
      for (int kk = 0; kk < 2; ++kk)
        af[m][kk] = *(const bf16x8*)(cA + (arowb + m * 16) * 128 +
                                     ((((kk << 2) | lk) ^ sx) << 4));
#pragma unroll
    for (int n = 0; n < 7; ++n)
#pragma unroll
      for (int kk = 0; kk < 2; ++kk)
        bf[n][kk] = *(const bf16x8*)(cB + (browb + n * 16) * 128 +
                                     ((((kk << 2) | lk) ^ sx) << 4));

    if (t + 1 < NT) {
      char* nA = sA + ((t + 1) & 1) * 32768;
      const bf16* g = aStage + (long)(t + 1) * 64;
#pragma unroll
      for (int i = 0; i < 4; ++i)
        async_copy16(nA + i * 8192 + wOff, g + (long)i * 64 * DALL);
    }
    const int more = (t + 2 < NT);
    if (more) {
      char* nB = sB + ((t + 2) % 3) * 28672;
      const bf16* g = bStage + (long)(t + 2) * 64;
#pragma unroll
      for (int i = 0; i < 3; ++i)
        async_copy16(nB + i * 8192 + wOff, g + (long)i * 64 * DALL);
      if (loWave)
        async_copy16(nB + 24576 + wOff, g + (long)192 * DALL);
    }

    __builtin_amdgcn_s_setprio(1);
#pragma unroll
    for (int m = 0; m < 4; ++m)
#pragma unroll
      for (int n = 0; n < 7; ++n)
#pragma unroll
        for (int kk = 0; kk < 2; ++kk)
          acc[m][n] = __builtin_amdgcn_mfma_f32_16x16x32_bf16(
              af[m][kk], bf[n][kk], acc[m][n], 0, 0, 0);
    __builtin_amdgcn_s_setprio(0);

    LGKM0();
    if (more) {
      if (loWave) { VMCNT4(); } else { VMCNT3(); }
    } else {
      VMCNT0();
    }
    BARRIER();
  }

#pragma unroll
  for (int m = 0; m < 4; ++m) {
#pragma unroll
    for (int n = 0; n < 7; ++n) {
      const int gc = col0 + wn * 112 + n * 16 + lr;
      const float bia = bias[gc];
#pragma unroll
      for (int j = 0; j < 4; ++j) {
        const int gr = row0 + wm * 64 + m * 16 + lk * 4 + j;
        Cout[(long)gr * DALL + gc] = __float2bfloat16(acc[m][n][j] + bia);
      }
    }
  }
}

// ---------------- key transpose: kT[d][s] = keys[s][d] (r15/r18) -----------
__global__ __launch_bounds__(256)
void keyt_kernel(const float* __restrict__ pkeys, const float* __restrict__ mkeys,
                 float* __restrict__ pkT, float* __restrict__ mkT) {
  const int tid = threadIdx.x;
  if (blockIdx.x == 0) {
    for (int i = tid; i < PDIM * NSLOT; i += 256) {
      const int d = i >> 6, s = i & 63;
      pkT[i] = pkeys[s * PDIM + d];
    }
  } else {
    const int b = (int)blockIdx.x - 1;
    for (int i = b * 8192 + tid; i < (b + 1) * 8192; i += 256) {
      const int d = i >> 6, s = i & 63;
      mkT[i] = mkeys[s * MDIM + d];
    }
  }
}

// ---------------- merged: vals + pw T(32) + w2 T(64) + prep (r15/r18) ------
__global__ __launch_bounds__(256)
void all_conv(const float* __restrict__ pv, const float* __restrict__ mv,
              bf16* __restrict__ pvb, bf16* __restrict__ mvb,
              const float* __restrict__ pw, bf16* __restrict__ pwTb,
              const float* __restrict__ w2, bf16* __restrict__ w2t,
              const float* __restrict__ ps, const float* __restrict__ mac,
              const float* __restrict__ pkT, const float* __restrict__ mkT,
              bf16* __restrict__ psb, bf16* __restrict__ att) {
  __shared__ __align__(16) char lsmem[9728];
  const int idx = blockIdx.x, tid = threadIdx.x;
  if (idx >= 4256) {
    float* q = (float*)lsmem;
    float* mrow = q + PDIM;
    float (*red)[PDIM] = (float(*)[PDIM])(mrow + MDIM);
    const int b = idx - 4256;
    const float* prow = ps + (long)b * DALL;
    if (tid < MDIM) mrow[tid] = mac[(long)b * MDIM + tid];
    float a8[8];
#pragma unroll
    for (int j = 0; j < 8; ++j) a8[j] = 0.f;
    for (int i = tid * 8; i < DALL; i += 2048) {
      float4 a = *(const float4*)(prow + i);
      float4 c = *(const float4*)(prow + i + 4);
      union { bf16 h[8]; bf16x8 v; } u;
      u.h[0] = __float2bfloat16(a.x); u.h[1] = __float2bfloat16(a.y);
      u.h[2] = __float2bfloat16(a.z); u.h[3] = __float2bfloat16(a.w);
      u.h[4] = __float2bfloat16(c.x); u.h[5] = __float2bfloat16(c.y);
      u.h[6] = __float2bfloat16(c.z); u.h[7] = __float2bfloat16(c.w);
      *(bf16x8*)(psb + (long)b * DALL + i) = u.v;
      a8[0] += a.x; a8[1] += a.y; a8[2] += a.z; a8[3] += a.w;
      a8[4] += c.x; a8[5] += c.y; a8[6] += c.z; a8[7] += c.w;
    }
    {
      float* rp = &red[tid >> 4][(tid & 15) * 8];
      *(f32x4*)rp = *(f32x4*)&a8[0];
      *(f32x4*)(rp + 4) = *(f32x4*)&a8[4];
    }
    __syncthreads();
    if (tid < PDIM) {
      float s = 0.f;
#pragma unroll
      for (int k = 0; k < 16; ++k) s += red[k][tid];
      q[tid] = s * (1.f / NPAIR);
    }
    __syncthreads();
    const int wid = tid >> 6, lane = tid & 63;
    if (wid == 0) {
      float s0 = 0.f, s1 = 0.f, s2 = 0.f, s3 = 0.f;
#pragma unroll
      for (int d = 0; d < PDIM; d += 4) {
        s0 += q[d] * pkT[d * 64 + lane];
        s1 += q[d + 1] * pkT[(d + 1) * 64 + lane];
        s2 += q[d + 2] * pkT[(d + 2) * 64 + lane];
        s3 += q[d + 3] * pkT[(d + 3) * 64 + lane];
      }
      float sc = ((s0 + s1) + (s2 + s3)) * 0.08838834764831845f;
      float mx = sc;
#pragma unroll
      for (int m = 32; m; m >>= 1) mx = fmaxf(mx, __shfl_xor(mx, m));
      float e = expf(sc - mx);
      float ssum = e;
#pragma unroll
      for (int m = 32; m; m >>= 1) ssum += __shfl_xor(ssum, m);
      att[(long)b * 128 + lane] = __float2bfloat16(e / ssum);
    } else if (wid == 1) {
      float s0 = 0.f, s1 = 0.f, s2 = 0.f, s3 = 0.f;
#pragma unroll
      for (int d = 0; d < MDIM; d += 4) {
        s0 += mrow[d] * mkT[d * 64 + lane];
        s1 += mrow[d + 1] * mkT[(d + 1) * 64 + lane];
        s2 += mrow[d + 2] * mkT[(d + 2) * 64 + lane];
        s3 += mrow[d + 3] * mkT[(d + 3) * 64 + lane];
      }
      float sc = ((s0 + s1) + (s2 + s3)) * 0.0625f;
      float mx = sc;
#pragma unroll
      for (int m = 32; m; m >>= 1) mx = fmaxf(mx, __shfl_xor(mx, m));
      float e = expf(sc - mx);
      float ssum = e;
#pragma unroll
      for (int m = 32; m; m >>= 1) ssum += __shfl_xor(ssum, m);
      att[(long)b * 128 + 64 + lane] = __float2bfloat16(e / ssum);
    }
    return;
  }
  if (idx < 224) {
    const int sel = idx >= 112;
    const float* in = sel ? mv : pv;
    bf16* out = sel ? mvb : pvb;
    const int bx = sel ? idx - 112 : idx;
    const int i = (bx * 256 + tid) * 8;
    float4 a = *(const float4*)(in + i);
    float4 b = *(const float4*)(in + i + 4);
    union { bf16 h[8]; bf16x8 v; } u;
    u.h[0] = __float2bfloat16(a.x); u.h[1] = __float2bfloat16(a.y);
    u.h[2] = __float2bfloat16(a.z); u.h[3] = __float2bfloat16(a.w);
    u.h[4] = __float2bfloat16(b.x); u.h[5] = __float2bfloat16(b.y);
    u.h[6] = __float2bfloat16(b.z); u.h[7] = __float2bfloat16(b.w);
    *(bf16x8*)(out + i) = u.v;
    return;
  }
  if (idx < 1120) {
    float (*tile)[33] = (float(*)[33])lsmem;
    const int t = idx - 224;
    const int c0 = (t & 3) * 32;
    const int r0 = ((t >> 2) & 7) * 32;
    const long base = (long)(t >> 5) * (MDIM * PDIM);
    const int tx = tid & 31, ty = tid >> 5;
#pragma unroll
    for (int i = 0; i < 4; ++i)
      tile[ty + i * 8][tx] = pw[base + (long)(r0 + ty + i * 8) * PDIM + c0 + tx];
    __syncthreads();
    const int cl = tid >> 3, rq = (tid & 7) * 4;
    union { bf16 h[4]; short4v v; } u;
#pragma unroll
    for (int j = 0; j < 4; ++j) u.h[j] = __float2bfloat16(tile[rq + j][cl]);
    *(short4v*)(pwTb + base + (long)(c0 + cl) * MDIM + r0 + rq) = u.v;
    return;
  }
  {
    bf16 (*s64)[72] = (bf16(*)[72])lsmem;
    const int t = idx - 1120;
    const int c0 = (t % 56) * 64, r0 = (t / 56) * 64;
    const int rr = tid >> 4, cc = (tid & 15) * 4;
#pragma unroll
    for (int i = 0; i < 4; ++i) {
      float4 v = *(const float4*)(w2 + (long)(r0 + rr + i * 16) * DALL + c0 + cc);
      union { bf16 h[4]; short4v s; } u;
      u.h[0] = __float2bfloat16(v.x); u.h[1] = __float2bfloat16(v.y);
      u.h[2] = __float2bfloat16(v.z); u.h[3] = __float2bfloat16(v.w);
      *(short4v*)&s64[rr + i * 16][cc] = u.s;
    }
    __syncthreads();
    const int oq = tid >> 6, oc = tid & 63;
    union { bf16 h[16]; bf16x8 v[2]; } u;
#pragma unroll
    for (int j = 0; j < 16; ++j) u.h[j] = s64[oq * 16 + j][oc];
    bf16* dst = w2t + (long)(c0 + oc) * DALL + r0 + oq * 16;
    *(bf16x8*)dst = u.v[0];
    *(bf16x8*)(dst + 8) = u.v[1];
  }
}

// ---------------- CVt precompute DIRECT from fp32 w1 (KSPLIT=32, r15) ------
__global__ __launch_bounds__(256)
void precompute_direct(const float* __restrict__ w1, const bf16* __restrict__ pvb,
                       const bf16* __restrict__ mvb, float* __restrict__ part) {
  __shared__ __align__(16) bf16 sAt[256 * 40];
  __shared__ __align__(16) bf16 sBt[64 * 32];
  const int tid = threadIdx.x, wid = tid >> 6, lane = tid & 63;
  const int lr = lane & 15, lk = lane >> 4;
  const int n0 = blockIdx.x * 256;
  const int ksb = blockIdx.y;
  const int kbase = ksb * KCH2;
  const bf16* vb = (ksb < 16) ? pvb : mvb;
  const int kcol0 = (ksb < 16) ? kbase : kbase - DALL;

  const int bs = tid >> 2;
  const int bgs = (tid & 3) ^ (bs & 3);

  f32x4 acc[4][4];
  const f32x4 zero = {0.f, 0.f, 0.f, 0.f};
#pragma unroll
  for (int m = 0; m < 4; ++m)
#pragma unroll
    for (int n = 0; n < 4; ++n) acc[m][n] = zero;

  for (int kt = 0; kt < KCH2; kt += 32) {
    __syncthreads();
    {
      const float* src = w1 + (long)(kbase + kt) * DALL + n0 + tid;
      bf16* dst = sAt + tid * 40;
#pragma unroll
      for (int r8 = 0; r8 < 32; r8 += 4) {
        union { bf16 h[4]; short4v v; } u;
#pragma unroll
        for (int j = 0; j < 4; ++j)
          u.h[j] = __float2bfloat16(src[(long)(r8 + j) * DALL]);
        *(short4v*)(dst + r8) = u.v;
      }
    }
    async_copy16((char*)sBt + tid * 16,
                 vb + (long)bs * DALL + kcol0 + kt + bgs * 8);
    __syncthreads();
    bf16x8 af[4], bfr[4];
#pragma unroll
    for (int m = 0; m < 4; ++m)
      af[m] = *(const bf16x8*)((const char*)sAt +
                               ((wid * 64 + m * 16 + lr) * 40 + lk * 8) * 2);
#pragma unroll
    for (int n = 0; n < 4; ++n) {
      const int s = n * 16 + lr;
      bfr[n] = *(const bf16x8*)((const char*)sBt + s * 64 + ((lk ^ (s & 3)) << 4));
    }
#pragma unroll
    for (int m = 0; m < 4; ++m)
#pragma unroll
      for (int n = 0; n < 4; ++n)
        acc[m][n] =
            __builtin_amdgcn_mfma_f32_16x16x32_bf16(af[m], bfr[n], acc[m][n], 0, 0, 0);
  }
#pragma unroll
  for (int m = 0; m < 4; ++m)
#pragma unroll
    for (int n = 0; n < 4; ++n)
#pragma unroll
      for (int j = 0; j < 4; ++j) {
        const int gn = n0 + wid * 64 + m * 16 + lk * 4 + j;
        const int s = n * 16 + lr;
        part[((long)ksb * DALL + gn) * 64 + s] = acc[m][n][j];
      }
}

// ---------------- reduce K-split partials -> CVt bf16 [3584][128] ----------
__global__ __launch_bounds__(256)
void reduce_cvt(const float* __restrict__ part, bf16* __restrict__ cvt) {
  const long i4 = ((long)blockIdx.x * 256 + threadIdx.x) * 4;
  const int n = (int)(i4 >> 7), sc = (int)(i4 & 127);
  const int half = sc >> 6, s0 = sc & 63;
  f32x4 s = {0.f, 0.f, 0.f, 0.f};
#pragma unroll
  for (int j = 0; j < 16; ++j)
    s += *(const f32x4*)(part + ((long)(half * 16 + j) * DALL + n) * 64 + s0);
#pragma unroll
  for (int k = 0; k < 4; ++k) cvt[i4 + k] = __float2bfloat16(s[k]);
}

// ---------------- thin GEMM K=128 (BK=64, swizzled, r7/r15) ----------------
__global__ __launch_bounds__(256)
void gemm_thin(const bf16* __restrict__ att, const bf16* __restrict__ cvt,
               bf16* __restrict__ hpre, const float* __restrict__ bias) {
  __shared__ __align__(16) bf16 sA[128 * 64];
  __shared__ __align__(16) bf16 sB[128 * 64];
  const int tid = threadIdx.x, wid = tid >> 6, lane = tid & 63;
  const int lr = lane & 15, lk = lane >> 4;
  const int col0 = blockIdx.x * 128, row0 = blockIdx.y * 128;
  const int srl = lane >> 3;
  const int sgl = (lane & 7) ^ srl;
  const int sx = lr & 7;

  f32x4 acc[2][8];
  const f32x4 zero = {0.f, 0.f, 0.f, 0.f};
#pragma unroll
  for (int m = 0; m < 2; ++m)
#pragma unroll
    for (int n = 0; n < 8; ++n) acc[m][n] = zero;

  for (int kt = 0; kt < 2; ++kt) {
    __syncthreads();
#pragma unroll
    for (int i = 0; i < 4; ++i) {
      const int r = i * 32 + wid * 8 + srl;
      async_copy16((char*)sA + i * 4096 + wid * 1024,
                   att + (long)(row0 + r) * 128 + kt * 64 + sgl * 8);
      async_copy16((char*)sB + i * 4096 + wid * 1024,
                   cvt + (long)(col0 + r) * 128 + kt * 64 + sgl * 8);
    }
    __syncthreads();
#pragma unroll
    for (int kk = 0; kk < 2; ++kk) {
      bf16x8 a0[2], b0[8];
      const int gb = (((kk << 2) | lk) ^ sx) << 4;
#pragma unroll
      for (int m = 0; m < 2; ++m)
        a0[m] = *(const bf16x8*)((const char*)sA + (wid * 32 + m * 16 + lr) * 128 + gb);
#pragma unroll
      for (int n = 0; n < 8; ++n)
        b0[n] = *(const bf16x8*)((const char*)sB + (n * 16 + lr) * 128 + gb);
#pragma unroll
      for (int m = 0; m < 2; ++m)
#pragma unroll
        for (int n = 0; n < 8; ++n)
          acc[m][n] = __builtin_amdgcn_mfma_f32_16x16x32_bf16(
              a0[m], b0[n], acc[m][n], 0, 0, 0);
    }
  }
#pragma unroll
  for (int m = 0; m < 2; ++m) {
#pragma unroll
    for (int n = 0; n < 8; ++n) {
      const int gc = col0 + n * 16 + lr;
      const float bia = bias[gc];
#pragma unroll
      for (int j = 0; j < 4; ++j) {
        const int gr = row0 + wid * 32 + m * 16 + lk * 4 + j;
        hpre[(long)gr * DALL + gc] = __float2bfloat16(acc[m][n][j] + bia);
      }
    }
  }
}

// ---------------- LayerNorm + exact GELU, scalar coalesced (r15/r18) -------
__global__ __launch_bounds__(256)
void ln_gelu_kernel(const bf16* __restrict__ h, const float* __restrict__ g,
                    const float* __restrict__ bb, bf16* __restrict__ h2) {
  const int row = blockIdx.x, tid = threadIdx.x;
  const bf16* x = h + (long)row * DALL;
  float v[14];
  float s1 = 0.f, s2 = 0.f;
#pragma unroll
  for (int i = 0; i < 14; ++i) {
    v[i] = __bfloat162float(x[i * 256 + tid]);
    s1 += v[i];
    s2 += v[i] * v[i];
  }
#pragma unroll
  for (int m = 32; m; m >>= 1) {
    s1 += __shfl_xor(s1, m);
    s2 += __shfl_xor(s2, m);
  }
  __shared__ float r1[4], r2[4];
  const int wid = tid >> 6, lane = tid & 63;
  if (lane == 0) {
    r1[wid] = s1;
    r2[wid] = s2;
  }
  __syncthreads();
  s1 = r1[0] + r1[1] + r1[2] + r1[3];
  s2 = r2[0] + r2[1] + r2[2] + r2[3];
  const float mean = s1 * (1.f / DALL);
  const float var = s2 * (1.f / DALL) - mean * mean;
  const float rstd = rsqrtf(var + 1e-5f);
#pragma unroll
  for (int i = 0; i < 14; ++i) {
    const int c = i * 256 + tid;
    const float y = (v[i] - mean) * rstd * g[c] + bb[c];
    const float ge = 0.5f * y * (1.f + erff(y * 0.7071067811865475f));
    h2[(long)row * DALL + c] = __float2bfloat16(ge);
  }
}

// ---------------- per-pair GEMM (K=256) + LN, NOW double-buffered ----------
// Clone of gemm224's 2-phase: stage kt+1 at iteration top (HBM latency hides
// under kt's 20 ds_reads + 32 MFMA); LGKM0+VMCNT0+BARRIER per iteration.
// LDS 64KB -> 2 blocks/CU. Overwrite of buf[kt&1] by stage(kt+2) is one
// barrier past kt's reads, which LGKM0 retired.
__global__ __launch_bounds__(256)
void pair_final(const bf16* __restrict__ psb, const bf16* __restrict__ fusedb,
                const bf16* __restrict__ pwT, const float* __restrict__ pb,
                const float* __restrict__ lng, const float* __restrict__ lnb,
                float* __restrict__ out) {
  __shared__ __align__(16) bf16 sA[2][128 * 64];
  __shared__ __align__(16) bf16 sB[2][128 * 64];
  const int tid = threadIdx.x, wid = tid >> 6, lane = tid & 63;
  const int lr = lane & 15, lk = lane >> 4;
  const int p = blockIdx.y, row0 = blockIdx.x * 128;
  const int srl = lane >> 3;
  const int sgl = (lane & 7) ^ srl;
  const int sx = lr & 7;
  const bf16* pwp = pwT + (long)p * (PDIM * MDIM);

  f32x4 acc[2][8];
  const f32x4 zero = {0.f, 0.f, 0.f, 0.f};
#pragma unroll
  for (int m = 0; m < 2; ++m)
#pragma unroll
    for (int n = 0; n < 8; ++n) acc[m][n] = zero;

  // stage tile kt into buffer b (8 async issues/thread)
  auto STAGE = [&](int kt, int b) {
    const bf16* Asrc = (kt < 2) ? psb : fusedb;
    const int acol = p * PDIM + (kt & 1) * 64;
#pragma unroll
    for (int i = 0; i < 4; ++i) {
      const int r = i * 32 + wid * 8 + srl;
      async_copy16((char*)sA[b] + i * 4096 + wid * 1024,
                   Asrc + (long)(row0 + r) * DALL + acol + sgl * 8);
      async_copy16((char*)sB[b] + i * 4096 + wid * 1024,
                   pwp + (long)r * MDIM + kt * 64 + sgl * 8);
    }
  };

  STAGE(0, 0);
  VMCNT0();
  BARRIER();

  for (int kt = 0; kt < 4; ++kt) {
    const int cur = kt & 1;
    if (kt + 1 < 4) STAGE(kt + 1, cur ^ 1);
#pragma unroll
    for (int kk = 0; kk < 2; ++kk) {
      bf16x8 a0[2], b0[8];
      const int gb = (((kk << 2) | lk) ^ sx) << 4;
#pragma unroll
      for (int m = 0; m < 2; ++m)
        a0[m] = *(const bf16x8*)((const char*)sA[cur] +
                                 (wid * 32 + m * 16 + lr) * 128 + gb);
#pragma unroll
      for (int n = 0; n < 8; ++n)
        b0[n] = *(const bf16x8*)((const char*)sB[cur] + (n * 16 + lr) * 128 + gb);
      __builtin_amdgcn_s_setprio(1);
#pragma unroll
      for (int m = 0; m < 2; ++m)
#pragma unroll
        for (int n = 0; n < 8; ++n)
          acc[m][n] = __builtin_amdgcn_mfma_f32_16x16x32_bf16(
              a0[m], b0[n], acc[m][n], 0, 0, 0);
      __builtin_amdgcn_s_setprio(0);
    }
    LGKM0();
    VMCNT0();
    BARRIER();
  }

  // LN epilogue (r18-identical)
  float g_[8], b_[8], pb_[8];
#pragma unroll
  for (int n = 0; n < 8; ++n) {
    const int c = n * 16 + lr;
    g_[n] = lng[p * PDIM + c];
    b_[n] = lnb[p * PDIM + c];
    pb_[n] = pb[p * PDIM + c];
  }
#pragma unroll
  for (int m = 0; m < 2; ++m) {
#pragma unroll
    for (int j = 0; j < 4; ++j) {
      float vv[8];
      float s1 = 0.f, s2 = 0.f;
#pragma unroll
      for (int n = 0; n < 8; ++n) {
        vv[n] = acc[m][n][j] + pb_[n];
        s1 += vv[n];
        s2 += vv[n] * vv[n];
      }
#pragma unroll
      for (int msk = 1; msk <= 8; msk <<= 1) {
        s1 += __shfl_xor(s1, msk);
        s2 += __shfl_xor(s2, msk);
      }
      const float mean = s1 * (1.f / 128.f);
      const float var = s2 * (1.f / 128.f) - mean * mean;
      const float rstd = rsqrtf(var + 1e-5f);
      const int gr = row0 + wid * 32 + m * 16 + lk * 4 + j;
      float* orow = out + ((long)gr * NPAIR + p) * PDIM;
#pragma unroll
      for (int n = 0; n < 8; ++n)
        orow[n * 16 + lr] = (vv[n] - mean) * rstd * g_[n] + b_[n];
    }
  }
}

// ---------------------------------------------------------------------------
extern "C" void kernel_launch(void* const* d_in, const int* in_sizes, int n_in,
                              void* d_out, int out_size, void* d_ws, size_t ws_size,
                              hipStream_t stream) {
  (void)in_sizes; (void)n_in; (void)out_size; (void)ws_size;
  const float* ps   = (const float*)d_in[0];
  const float* mac  = (const float*)d_in[1];
  const float* pkey = (const float*)d_in[2];
  const float* pval = (const float*)d_in[3];
  const float* mkey = (const float*)d_in[4];
  const float* mval = (const float*)d_in[5];
  const float* w1   = (const float*)d_in[6];
  const float* b1   = (const float*)d_in[7];
  const float* lng1 = (const float*)d_in[8];
  const float* lnb1 = (const float*)d_in[9];
  const float* w2   = (const float*)d_in[10];
  const float* b2   = (const float*)d_in[11];
  const float* pw   = (const float*)d_in[12];
  const float* pb   = (const float*)d_in[13];
  const float* plng = (const float*)d_in[14];
  const float* plnb = (const float*)d_in[15];
  float* out = (float*)d_out;

  char* w = (char*)d_ws;
  size_t off = 0;
  auto carve = [&](size_t bytes) {
    char* pp = w + off;
    off += (bytes + 255) & ~(size_t)255;
    return pp;
  };
  bf16* psb   = (bf16*)carve((size_t)B_SZ * DALL * 2);
  bf16* w2t   = (bf16*)carve((size_t)(DALL + 32) * DALL * 2);  // +32 pad rows
  bf16* pvb   = (bf16*)carve((size_t)NSLOT * DALL * 2);
  bf16* mvb   = (bf16*)carve((size_t)NSLOT * DALL * 2);
  bf16* pwTb  = (bf16*)carve((size_t)NPAIR * PDIM * MDIM * 2);
  bf16* att   = (bf16*)carve((size_t)B_SZ * 128 * 2);
  bf16* cvt   = (bf16*)carve((size_t)DALL * 128 * 2);
  float* part = (float*)carve((size_t)KS2 * DALL * 64 * 4);    // 29.4 MB
  bf16* hpreb = (bf16*)carve((size_t)B_SZ * DALL * 2);
  bf16* h2    = (bf16*)carve((size_t)B_SZ * DALL * 2);
  float* pkT  = (float*)carve((size_t)PDIM * NSLOT * 4);
  float* mkT  = (float*)carve((size_t)MDIM * NSLOT * 4);
  bf16* fusedb = hpreb;  // alias: hpreb last read by ln_gelu

  keyt_kernel<<<dim3(3), 256, 0, stream>>>(pkey, mkey, pkT, mkT);
  all_conv<<<dim3(8352), 256, 0, stream>>>(pval, mval, pvb, mvb, pw, pwTb,
                                           w2, w2t, ps, mac, pkT, mkT, psb, att);
  precompute_direct<<<dim3(DALL / 256, KS2), 256, 0, stream>>>(w1, pvb, mvb, part);
  reduce_cvt<<<dim3(DALL * 128 / 1024), 256, 0, stream>>>(part, cvt);
  gemm_thin<<<dim3(DALL / 128, B_SZ / 128), 256, 0, stream>>>(att, cvt, hpreb, b1);
  ln_gelu_kernel<<<dim3(B_SZ), 256, 0, stream>>>(hpreb, lng1, lnb1, h2);
  gemm224<<<dim3(256), 512, 0, stream>>>(h2, w2t, fusedb, b2);
  pair_final<<<dim3(B_SZ / 128, NPAIR), 256, 0, stream>>>(
      psb, fusedb, pwTb, pb, plng, plnb, out);
}

// Round 20
// 243.579 us; speedup vs baseline: 1.0087x; 1.0087x over previous
//
#include <hip/hip_runtime.h>
#include <hip/hip_bf16.h>
#include <math.h>

// CrossPairMemory FINAL (round 20): exact r18 configuration (244.6us
// verified session best; r19's pair_final dbuf was neutral and is reverted).
// Pipeline: keyt -> all_conv(vals+pwT+w2T+prep) -> precompute_direct(w1,
// rank-128 factor) -> reduce -> gemm_thin -> ln_gelu -> gemm224(1-barrier
// A-dbuf/B-tribuf) -> pair_final.

#define B_SZ  4096
#define NPAIR 28
#define PDIM  128
#define MDIM  256
#define NSLOT 64
#define DALL  3584
#define DCAT  7168
#define KS2   32
#define KCH2  224   // DCAT / KS2

typedef __hip_bfloat16 bf16;
typedef __attribute__((ext_vector_type(8))) short bf16x8;
typedef __attribute__((ext_vector_type(4))) short short4v;
typedef __attribute__((ext_vector_type(4))) float f32x4;

#define BARRIER() asm volatile("s_barrier" ::: "memory")
#define LGKM0()   asm volatile("s_waitcnt lgkmcnt(0)" ::: "memory")
#define VMCNT4()  asm volatile("s_waitcnt vmcnt(4)" ::: "memory")
#define VMCNT3()  asm volatile("s_waitcnt vmcnt(3)" ::: "memory")
#define VMCNT0()  asm volatile("s_waitcnt vmcnt(0)" ::: "memory")

__device__ __forceinline__ void async_copy16(void* lds, const void* g) {
  __builtin_amdgcn_global_load_lds((__attribute__((address_space(1))) void*)g,
                                   (__attribute__((address_space(3))) void*)lds,
                                   16, 0, 0);
}

// ============== 256x224x64 1-barrier GEMM: A dbuf + B tribuf (r18) =========
__global__ __launch_bounds__(512, 2)
void gemm224(const bf16* __restrict__ A, const bf16* __restrict__ Bt,
             bf16* __restrict__ Cout, const float* __restrict__ bias) {
  __shared__ __align__(16) char smem[151552];   // 64KB A + 84KB B
  const int tid = threadIdx.x;
  const int wid = tid >> 6, lane = tid & 63;
  const int lr = lane & 15, lk = lane >> 4;
  const int wm = wid >> 1, wn = wid & 1;
  const int swz = ((int)blockIdx.x & 7) * 32 + ((int)blockIdx.x >> 3);
  const int bx = swz & 15, by = swz >> 4;
  const int col0 = bx * 224, row0 = by * 256;

  char* sA = smem;            // 2 x 32768
  char* sB = smem + 65536;    // 3 x 28672

  const int srow = tid >> 3;
  const int sg = (tid & 7) ^ (srow & 7);
  const bf16* aStage = A + (long)(row0 + srow) * DALL + sg * 8;
  const bf16* bStage = Bt + (long)(col0 + srow) * DALL + sg * 8;
  const int wOff = wid << 10;
  const int loWave = (wid < 4);

  const int NT = DALL >> 6;  // 56

  const int sx = lr & 7;
  const int arowb = wm * 64 + lr;
  const int browb = wn * 112 + lr;

  f32x4 acc[4][7];
  const f32x4 zero = {0.f, 0.f, 0.f, 0.f};
#pragma unroll
  for (int m = 0; m < 4; ++m)
#pragma unroll
    for (int n = 0; n < 7; ++n) acc[m][n] = zero;

#pragma unroll
  for (int i = 0; i < 4; ++i)
    async_copy16(sA + i * 8192 + wOff, aStage + (long)i * 64 * DALL);
#pragma unroll
  for (int i = 0; i < 3; ++i)
    async_copy16(sB + i * 8192 + wOff, bStage + (long)i * 64 * DALL);
  if (loWave)
    async_copy16(sB + 24576 + wOff, bStage + (long)192 * DALL);
#pragma unroll
  for (int i = 0; i < 3; ++i)
    async_copy16(sB + 28672 + i * 8192 + wOff, bStage + (long)i * 64 * DALL + 64);
  if (loWave)
    async_copy16(sB + 28672 + 24576 + wOff, bStage + (long)192 * DALL + 64);
  if (loWave) { VMCNT4(); } else { VMCNT3(); }
  BARRIER();

  bf16x8 af[4][2], bf[7][2];

  for (int t = 0; t < NT; ++t) {
    char* cA = sA + (t & 1) * 32768;
    char* cB = sB + (t % 3) * 28672;

#pragma unroll
    for (int m = 0; m < 4; ++m)
#pragma unroll
      for (int kk = 0; kk < 2; ++kk)
        af[m][kk] = *(const bf16x8*)(cA + (arowb + m * 16) * 128 +
                                     ((((kk << 2) | lk) ^ sx) << 4));
#pragma unroll
    for (int n = 0; n < 7; ++n)
#pragma unroll
      for (int kk = 0; kk < 2; ++kk)
        bf[n][kk] = *(const bf16x8*)(cB + (browb + n * 16) * 128 +
                                     ((((kk << 2) | lk) ^ sx) << 4));

    if (t + 1 < NT) {
      char* nA = sA + ((t + 1) & 1) * 32768;
      const bf16* g = aStage + (long)(t + 1) * 64;
#pragma unroll
      for (int i = 0; i < 4; ++i)
        async_copy16(nA + i * 8192 + wOff, g + (long)i * 64 * DALL);
    }
    const int more = (t + 2 < NT);
    if (more) {
      char* nB = sB + ((t + 2) % 3) * 28672;
      const bf16* g = bStage + (long)(t + 2) * 64;
#pragma unroll
      for (int i = 0; i < 3; ++i)
        async_copy16(nB + i * 8192 + wOff, g + (long)i * 64 * DALL);
      if (loWave)
        async_copy16(nB + 24576 + wOff, g + (long)192 * DALL);
    }

    __builtin_amdgcn_s_setprio(1);
#pragma unroll
    for (int m = 0; m < 4; ++m)
#pragma unroll
      for (int n = 0; n < 7; ++n)
#pragma unroll
        for (int kk = 0; kk < 2; ++kk)
          acc[m][n] = __builtin_amdgcn_mfma_f32_16x16x32_bf16(
              af[m][kk], bf[n][kk], acc[m][n], 0, 0, 0);
    __builtin_amdgcn_s_setprio(0);

    LGKM0();
    if (more) {
      if (loWave) { VMCNT4(); } else { VMCNT3(); }
    } else {
      VMCNT0();
    }
    BARRIER();
  }

#pragma unroll
  for (int m = 0; m < 4; ++m) {
#pragma unroll
    for (int n = 0; n < 7; ++n) {
      const int gc = col0 + wn * 112 + n * 16 + lr;
      const float bia = bias[gc];
#pragma unroll
      for (int j = 0; j < 4; ++j) {
        const int gr = row0 + wm * 64 + m * 16 + lk * 4 + j;
        Cout[(long)gr * DALL + gc] = __float2bfloat16(acc[m][n][j] + bia);
      }
    }
  }
}

// ---------------- key transpose: kT[d][s] = keys[s][d] (r15/r18) -----------
__global__ __launch_bounds__(256)
void keyt_kernel(const float* __restrict__ pkeys, const float* __restrict__ mkeys,
                 float* __restrict__ pkT, float* __restrict__ mkT) {
  const int tid = threadIdx.x;
  if (blockIdx.x == 0) {
    for (int i = tid; i < PDIM * NSLOT; i += 256) {
      const int d = i >> 6, s = i & 63;
      pkT[i] = pkeys[s * PDIM + d];
    }
  } else {
    const int b = (int)blockIdx.x - 1;
    for (int i = b * 8192 + tid; i < (b + 1) * 8192; i += 256) {
      const int d = i >> 6, s = i & 63;
      mkT[i] = mkeys[s * MDIM + d];
    }
  }
}

// ---------------- merged: vals + pw T(32) + w2 T(64) + prep (r15/r18) ------
__global__ __launch_bounds__(256)
void all_conv(const float* __restrict__ pv, const float* __restrict__ mv,
              bf16* __restrict__ pvb, bf16* __restrict__ mvb,
              const float* __restrict__ pw, bf16* __restrict__ pwTb,
              const float* __restrict__ w2, bf16* __restrict__ w2t,
              const float* __restrict__ ps, const float* __restrict__ mac,
              const float* __restrict__ pkT, const float* __restrict__ mkT,
              bf16* __restrict__ psb, bf16* __restrict__ att) {
  __shared__ __align__(16) char lsmem[9728];
  const int idx = blockIdx.x, tid = threadIdx.x;
  if (idx >= 4256) {
    float* q = (float*)lsmem;
    float* mrow = q + PDIM;
    float (*red)[PDIM] = (float(*)[PDIM])(mrow + MDIM);
    const int b = idx - 4256;
    const float* prow = ps + (long)b * DALL;
    if (tid < MDIM) mrow[tid] = mac[(long)b * MDIM + tid];
    float a8[8];
#pragma unroll
    for (int j = 0; j < 8; ++j) a8[j] = 0.f;
    for (int i = tid * 8; i < DALL; i += 2048) {
      float4 a = *(const float4*)(prow + i);
      float4 c = *(const float4*)(prow + i + 4);
      union { bf16 h[8]; bf16x8 v; } u;
      u.h[0] = __float2bfloat16(a.x); u.h[1] = __float2bfloat16(a.y);
      u.h[2] = __float2bfloat16(a.z); u.h[3] = __float2bfloat16(a.w);
      u.h[4] = __float2bfloat16(c.x); u.h[5] = __float2bfloat16(c.y);
      u.h[6] = __float2bfloat16(c.z); u.h[7] = __float2bfloat16(c.w);
      *(bf16x8*)(psb + (long)b * DALL + i) = u.v;
      a8[0] += a.x; a8[1] += a.y; a8[2] += a.z; a8[3] += a.w;
      a8[4] += c.x; a8[5] += c.y; a8[6] += c.z; a8[7] += c.w;
    }
    {
      float* rp = &red[tid >> 4][(tid & 15) * 8];
      *(f32x4*)rp = *(f32x4*)&a8[0];
      *(f32x4*)(rp + 4) = *(f32x4*)&a8[4];
    }
    __syncthreads();
    if (tid < PDIM) {
      float s = 0.f;
#pragma unroll
      for (int k = 0; k < 16; ++k) s += red[k][tid];
      q[tid] = s * (1.f / NPAIR);
    }
    __syncthreads();
    const int wid = tid >> 6, lane = tid & 63;
    if (wid == 0) {
      float s0 = 0.f, s1 = 0.f, s2 = 0.f, s3 = 0.f;
#pragma unroll
      for (int d = 0; d < PDIM; d += 4) {
        s0 += q[d] * pkT[d * 64 + lane];
        s1 += q[d + 1] * pkT[(d + 1) * 64 + lane];
        s2 += q[d + 2] * pkT[(d + 2) * 64 + lane];
        s3 += q[d + 3] * pkT[(d + 3) * 64 + lane];
      }
      float sc = ((s0 + s1) + (s2 + s3)) * 0.08838834764831845f;
      float mx = sc;
#pragma unroll
      for (int m = 32; m; m >>= 1) mx = fmaxf(mx, __shfl_xor(mx, m));
      float e = expf(sc - mx);
      float ssum = e;
#pragma unroll
      for (int m = 32; m; m >>= 1) ssum += __shfl_xor(ssum, m);
      att[(long)b * 128 + lane] = __float2bfloat16(e / ssum);
    } else if (wid == 1) {
      float s0 = 0.f, s1 = 0.f, s2 = 0.f, s3 = 0.f;
#pragma unroll
      for (int d = 0; d < MDIM; d += 4) {
        s0 += mrow[d] * mkT[d * 64 + lane];
        s1 += mrow[d + 1] * mkT[(d + 1) * 64 + lane];
        s2 += mrow[d + 2] * mkT[(d + 2) * 64 + lane];
        s3 += mrow[d + 3] * mkT[(d + 3) * 64 + lane];
      }
      float sc = ((s0 + s1) + (s2 + s3)) * 0.0625f;
      float mx = sc;
#pragma unroll
      for (int m = 32; m; m >>= 1) mx = fmaxf(mx, __shfl_xor(mx, m));
      float e = expf(sc - mx);
      float ssum = e;
#pragma unroll
      for (int m = 32; m; m >>= 1) ssum += __shfl_xor(ssum, m);
      att[(long)b * 128 + 64 + lane] = __float2bfloat16(e / ssum);
    }
    return;
  }
  if (idx < 224) {
    const int sel = idx >= 112;
    const float* in = sel ? mv : pv;
    bf16* out = sel ? mvb : pvb;
    const int bx = sel ? idx - 112 : idx;
    const int i = (bx * 256 + tid) * 8;
    float4 a = *(const float4*)(in + i);
    float4 b = *(const float4*)(in + i + 4);
    union { bf16 h[8]; bf16x8 v; } u;
    u.h[0] = __float2bfloat16(a.x); u.h[1] = __float2bfloat16(a.y);
    u.h[2] = __float2bfloat16(a.z); u.h[3] = __float2bfloat16(a.w);
    u.h[4] = __float2bfloat16(b.x); u.h[5] = __float2bfloat16(b.y);
    u.h[6] = __float2bfloat16(b.z); u.h[7] = __float2bfloat16(b.w);
    *(bf16x8*)(out + i) = u.v;
    return;
  }
  if (idx < 1120) {
    float (*tile)[33] = (float(*)[33])lsmem;
    const int t = idx - 224;
    const int c0 = (t & 3) * 32;
    const int r0 = ((t >> 2) & 7) * 32;
    const long base = (long)(t >> 5) * (MDIM * PDIM);
    const int tx = tid & 31, ty = tid >> 5;
#pragma unroll
    for (int i = 0; i < 4; ++i)
      tile[ty + i * 8][tx] = pw[base + (long)(r0 + ty + i * 8) * PDIM + c0 + tx];
    __syncthreads();
    const int cl = tid >> 3, rq = (tid & 7) * 4;
    union { bf16 h[4]; short4v v; } u;
#pragma unroll
    for (int j = 0; j < 4; ++j) u.h[j] = __float2bfloat16(tile[rq + j][cl]);
    *(short4v*)(pwTb + base + (long)(c0 + cl) * MDIM + r0 + rq) = u.v;
    return;
  }
  {
    bf16 (*s64)[72] = (bf16(*)[72])lsmem;
    const int t = idx - 1120;
    const int c0 = (t % 56) * 64, r0 = (t / 56) * 64;
    const int rr = tid >> 4, cc = (tid & 15) * 4;
#pragma unroll
    for (int i = 0; i < 4; ++i) {
      float4 v = *(const float4*)(w2 + (long)(r0 + rr + i * 16) * DALL + c0 + cc);
      union { bf16 h[4]; short4v s; } u;
      u.h[0] = __float2bfloat16(v.x); u.h[1] = __float2bfloat16(v.y);
      u.h[2] = __float2bfloat16(v.z); u.h[3] = __float2bfloat16(v.w);
      *(short4v*)&s64[rr + i * 16][cc] = u.s;
    }
    __syncthreads();
    const int oq = tid >> 6, oc = tid & 63;
    union { bf16 h[16]; bf16x8 v[2]; } u;
#pragma unroll
    for (int j = 0; j < 16; ++j) u.h[j] = s64[oq * 16 + j][oc];
    bf16* dst = w2t + (long)(c0 + oc) * DALL + r0 + oq * 16;
    *(bf16x8*)dst = u.v[0];
    *(bf16x8*)(dst + 8) = u.v[1];
  }
}

// ---------------- CVt precompute DIRECT from fp32 w1 (KSPLIT=32, r15) ------
__global__ __launch_bounds__(256)
void precompute_direct(const float* __restrict__ w1, const bf16* __restrict__ pvb,
                       const bf16* __restrict__ mvb, float* __restrict__ part) {
  __shared__ __align__(16) bf16 sAt[256 * 40];
  __shared__ __align__(16) bf16 sBt[64 * 32];
  const int tid = threadIdx.x, wid = tid >> 6, lane = tid & 63;
  const int lr = lane & 15, lk = lane >> 4;
  const int n0 = blockIdx.x * 256;
  const int ksb = blockIdx.y;
  const int kbase = ksb * KCH2;
  const bf16* vb = (ksb < 16) ? pvb : mvb;
  const int kcol0 = (ksb < 16) ? kbase : kbase - DALL;

  const int bs = tid >> 2;
  const int bgs = (tid & 3) ^ (bs & 3);

  f32x4 acc[4][4];
  const f32x4 zero = {0.f, 0.f, 0.f, 0.f};
#pragma unroll
  for (int m = 0; m < 4; ++m)
#pragma unroll
    for (int n = 0; n < 4; ++n) acc[m][n] = zero;

  for (int kt = 0; kt < KCH2; kt += 32) {
    __syncthreads();
    {
      const float* src = w1 + (long)(kbase + kt) * DALL + n0 + tid;
      bf16* dst = sAt + tid * 40;
#pragma unroll
      for (int r8 = 0; r8 < 32; r8 += 4) {
        union { bf16 h[4]; short4v v; } u;
#pragma unroll
        for (int j = 0; j < 4; ++j)
          u.h[j] = __float2bfloat16(src[(long)(r8 + j) * DALL]);
        *(short4v*)(dst + r8) = u.v;
      }
    }
    async_copy16((char*)sBt + tid * 16,
                 vb + (long)bs * DALL + kcol0 + kt + bgs * 8);
    __syncthreads();
    bf16x8 af[4], bfr[4];
#pragma unroll
    for (int m = 0; m < 4; ++m)
      af[m] = *(const bf16x8*)((const char*)sAt +
                               ((wid * 64 + m * 16 + lr) * 40 + lk * 8) * 2);
#pragma unroll
    for (int n = 0; n < 4; ++n) {
      const int s = n * 16 + lr;
      bfr[n] = *(const bf16x8*)((const char*)sBt + s * 64 + ((lk ^ (s & 3)) << 4));
    }
#pragma unroll
    for (int m = 0; m < 4; ++m)
#pragma unroll
      for (int n = 0; n < 4; ++n)
        acc[m][n] =
            __builtin_amdgcn_mfma_f32_16x16x32_bf16(af[m], bfr[n], acc[m][n], 0, 0, 0);
  }
#pragma unroll
  for (int m = 0; m < 4; ++m)
#pragma unroll
    for (int n = 0; n < 4; ++n)
#pragma unroll
      for (int j = 0; j < 4; ++j) {
        const int gn = n0 + wid * 64 + m * 16 + lk * 4 + j;
        const int s = n * 16 + lr;
        part[((long)ksb * DALL + gn) * 64 + s] = acc[m][n][j];
      }
}

// ---------------- reduce K-split partials -> CVt bf16 [3584][128] ----------
__global__ __launch_bounds__(256)
void reduce_cvt(const float* __restrict__ part, bf16* __restrict__ cvt) {
  const long i4 = ((long)blockIdx.x * 256 + threadIdx.x) * 4;
  const int n = (int)(i4 >> 7), sc = (int)(i4 & 127);
  const int half = sc >> 6, s0 = sc & 63;
  f32x4 s = {0.f, 0.f, 0.f, 0.f};
#pragma unroll
  for (int j = 0; j < 16; ++j)
    s += *(const f32x4*)(part + ((long)(half * 16 + j) * DALL + n) * 64 + s0);
#pragma unroll
  for (int k = 0; k < 4; ++k) cvt[i4 + k] = __float2bfloat16(s[k]);
}

// ---------------- thin GEMM K=128 (BK=64, swizzled, r7/r15) ----------------
__global__ __launch_bounds__(256)
void gemm_thin(const bf16* __restrict__ att, const bf16* __restrict__ cvt,
               bf16* __restrict__ hpre, const float* __restrict__ bias) {
  __shared__ __align__(16) bf16 sA[128 * 64];
  __shared__ __align__(16) bf16 sB[128 * 64];
  const int tid = threadIdx.x, wid = tid >> 6, lane = tid & 63;
  const int lr = lane & 15, lk = lane >> 4;
  const int col0 = blockIdx.x * 128, row0 = blockIdx.y * 128;
  const int srl = lane >> 3;
  const int sgl = (lane & 7) ^ srl;
  const int sx = lr & 7;

  f32x4 acc[2][8];
  const f32x4 zero = {0.f, 0.f, 0.f, 0.f};
#pragma unroll
  for (int m = 0; m < 2; ++m)
#pragma unroll
    for (int n = 0; n < 8; ++n) acc[m][n] = zero;

  for (int kt = 0; kt < 2; ++kt) {
    __syncthreads();
#pragma unroll
    for (int i = 0; i < 4; ++i) {
      const int r = i * 32 + wid * 8 + srl;
      async_copy16((char*)sA + i * 4096 + wid * 1024,
                   att + (long)(row0 + r) * 128 + kt * 64 + sgl * 8);
      async_copy16((char*)sB + i * 4096 + wid * 1024,
                   cvt + (long)(col0 + r) * 128 + kt * 64 + sgl * 8);
    }
    __syncthreads();
#pragma unroll
    for (int kk = 0; kk < 2; ++kk) {
      bf16x8 a0[2], b0[8];
      const int gb = (((kk << 2) | lk) ^ sx) << 4;
#pragma unroll
      for (int m = 0; m < 2; ++m)
        a0[m] = *(const bf16x8*)((const char*)sA + (wid * 32 + m * 16 + lr) * 128 + gb);
#pragma unroll
      for (int n = 0; n < 8; ++n)
        b0[n] = *(const bf16x8*)((const char*)sB + (n * 16 + lr) * 128 + gb);
#pragma unroll
      for (int m = 0; m < 2; ++m)
#pragma unroll
        for (int n = 0; n < 8; ++n)
          acc[m][n] = __builtin_amdgcn_mfma_f32_16x16x32_bf16(
              a0[m], b0[n], acc[m][n], 0, 0, 0);
    }
  }
#pragma unroll
  for (int m = 0; m < 2; ++m) {
#pragma unroll
    for (int n = 0; n < 8; ++n) {
      const int gc = col0 + n * 16 + lr;
      const float bia = bias[gc];
#pragma unroll
      for (int j = 0; j < 4; ++j) {
        const int gr = row0 + wid * 32 + m * 16 + lk * 4 + j;
        hpre[(long)gr * DALL + gc] = __float2bfloat16(acc[m][n][j] + bia);
      }
    }
  }
}

// ---------------- LayerNorm + exact GELU, scalar coalesced (r15/r18) -------
__global__ __launch_bounds__(256)
void ln_gelu_kernel(const bf16* __restrict__ h, const float* __restrict__ g,
                    const float* __restrict__ bb, bf16* __restrict__ h2) {
  const int row = blockIdx.x, tid = threadIdx.x;
  const bf16* x = h + (long)row * DALL;
  float v[14];
  float s1 = 0.f, s2 = 0.f;
#pragma unroll
  for (int i = 0; i < 14; ++i) {
    v[i] = __bfloat162float(x[i * 256 + tid]);
    s1 += v[i];
    s2 += v[i] * v[i];
  }
#pragma unroll
  for (int m = 32; m; m >>= 1) {
    s1 += __shfl_xor(s1, m);
    s2 += __shfl_xor(s2, m);
  }
  __shared__ float r1[4], r2[4];
  const int wid = tid >> 6, lane = tid & 63;
  if (lane == 0) {
    r1[wid] = s1;
    r2[wid] = s2;
  }
  __syncthreads();
  s1 = r1[0] + r1[1] + r1[2] + r1[3];
  s2 = r2[0] + r2[1] + r2[2] + r2[3];
  const float mean = s1 * (1.f / DALL);
  const float var = s2 * (1.f / DALL) - mean * mean;
  const float rstd = rsqrtf(var + 1e-5f);
#pragma unroll
  for (int i = 0; i < 14; ++i) {
    const int c = i * 256 + tid;
    const float y = (v[i] - mean) * rstd * g[c] + bb[c];
    const float ge = 0.5f * y * (1.f + erff(y * 0.7071067811865475f));
    h2[(long)row * DALL + c] = __float2bfloat16(ge);
  }
}

// ---------------- per-pair GEMM (K=256, BK=64 swizzled) + LN (r18) ---------
__global__ __launch_bounds__(256)
void pair_final(const bf16* __restrict__ psb, const bf16* __restrict__ fusedb,
                const bf16* __restrict__ pwT, const float* __restrict__ pb,
                const float* __restrict__ lng, const float* __restrict__ lnb,
                float* __restrict__ out) {
  __shared__ __align__(16) bf16 sA[128 * 64];
  __shared__ __align__(16) bf16 sB[128 * 64];
  const int tid = threadIdx.x, wid = tid >> 6, lane = tid & 63;
  const int lr = lane & 15, lk = lane >> 4;
  const int p = blockIdx.y, row0 = blockIdx.x * 128;
  const int srl = lane >> 3;
  const int sgl = (lane & 7) ^ srl;
  const int sx = lr & 7;
  const bf16* pwp = pwT + (long)p * (PDIM * MDIM);

  f32x4 acc[2][8];
  const f32x4 zero = {0.f, 0.f, 0.f, 0.f};
#pragma unroll
  for (int m = 0; m < 2; ++m)
#pragma unroll
    for (int n = 0; n < 8; ++n) acc[m][n] = zero;

  for (int kt = 0; kt < 4; ++kt) {
    __syncthreads();
    const bf16* Asrc = (kt < 2) ? psb : fusedb;
    const int acol = p * PDIM + (kt & 1) * 64;
#pragma unroll
    for (int i = 0; i < 4; ++i) {
      const int r = i * 32 + wid * 8 + srl;
      async_copy16((char*)sA + i * 4096 + wid * 1024,
                   Asrc + (long)(row0 + r) * DALL + acol + sgl * 8);
      async_copy16((char*)sB + i * 4096 + wid * 1024,
                   pwp + (long)r * MDIM + kt * 64 + sgl * 8);
    }
    __syncthreads();
#pragma unroll
    for (int kk = 0; kk < 2; ++kk) {
      bf16x8 a0[2], b0[8];
      const int gb = (((kk << 2) | lk) ^ sx) << 4;
#pragma unroll
      for (int m = 0; m < 2; ++m)
        a0[m] = *(const bf16x8*)((const char*)sA + (wid * 32 + m * 16 + lr) * 128 + gb);
#pragma unroll
      for (int n = 0; n < 8; ++n)
        b0[n] = *(const bf16x8*)((const char*)sB + (n * 16 + lr) * 128 + gb);
#pragma unroll
      for (int m = 0; m < 2; ++m)
#pragma unroll
        for (int n = 0; n < 8; ++n)
          acc[m][n] = __builtin_amdgcn_mfma_f32_16x16x32_bf16(
              a0[m], b0[n], acc[m][n], 0, 0, 0);
    }
  }
  float g_[8], b_[8], pb_[8];
#pragma unroll
  for (int n = 0; n < 8; ++n) {
    const int c = n * 16 + lr;
    g_[n] = lng[p * PDIM + c];
    b_[n] = lnb[p * PDIM + c];
    pb_[n] = pb[p * PDIM + c];
  }
#pragma unroll
  for (int m = 0; m < 2; ++m) {
#pragma unroll
    for (int j = 0; j < 4; ++j) {
      float vv[8];
      float s1 = 0.f, s2 = 0.f;
#pragma unroll
      for (int n = 0; n < 8; ++n) {
        vv[n] = acc[m][n][j] + pb_[n];
        s1 += vv[n];
        s2 += vv[n] * vv[n];
      }
#pragma unroll
      for (int msk = 1; msk <= 8; msk <<= 1) {
        s1 += __shfl_xor(s1, msk);
        s2 += __shfl_xor(s2, msk);
      }
      const float mean = s1 * (1.f / 128.f);
      const float var = s2 * (1.f / 128.f) - mean * mean;
      const float rstd = rsqrtf(var + 1e-5f);
      const int gr = row0 + wid * 32 + m * 16 + lk * 4 + j;
      float* orow = out + ((long)gr * NPAIR + p) * PDIM;
#pragma unroll
      for (int n = 0; n < 8; ++n)
        orow[n * 16 + lr] = (vv[n] - mean) * rstd * g_[n] + b_[n];
    }
  }
}

// ---------------------------------------------------------------------------
extern "C" void kernel_launch(void* const* d_in, const int* in_sizes, int n_in,
                              void* d_out, int out_size, void* d_ws, size_t ws_size,
                              hipStream_t stream) {
  (void)in_sizes; (void)n_in; (void)out_size; (void)ws_size;
  const float* ps   = (const float*)d_in[0];
  const float* mac  = (const float*)d_in[1];
  const float* pkey = (const float*)d_in[2];
  const float* pval = (const float*)d_in[3];
  const float* mkey = (const float*)d_in[4];
  const float* mval = (const float*)d_in[5];
  const float* w1   = (const float*)d_in[6];
  const float* b1   = (const float*)d_in[7];
  const float* lng1 = (const float*)d_in[8];
  const float* lnb1 = (const float*)d_in[9];
  const float* w2   = (const float*)d_in[10];
  const float* b2   = (const float*)d_in[11];
  const float* pw   = (const float*)d_in[12];
  const float* pb   = (const float*)d_in[13];
  const float* plng = (const float*)d_in[14];
  const float* plnb = (const float*)d_in[15];
  float* out = (float*)d_out;

  char* w = (char*)d_ws;
  size_t off = 0;
  auto carve = [&](size_t bytes) {
    char* pp = w + off;
    off += (bytes + 255) & ~(size_t)255;
    return pp;
  };
  bf16* psb   = (bf16*)carve((size_t)B_SZ * DALL * 2);
  bf16* w2t   = (bf16*)carve((size_t)(DALL + 32) * DALL * 2);  // +32 pad rows
  bf16* pvb   = (bf16*)carve((size_t)NSLOT * DALL * 2);
  bf16* mvb   = (bf16*)carve((size_t)NSLOT * DALL * 2);
  bf16* pwTb  = (bf16*)carve((size_t)NPAIR * PDIM * MDIM * 2);
  bf16* att   = (bf16*)carve((size_t)B_SZ * 128 * 2);
  bf16* cvt   = (bf16*)carve((size_t)DALL * 128 * 2);
  float* part = (float*)carve((size_t)KS2 * DALL * 64 * 4);    // 29.4 MB
  bf16* hpreb = (bf16*)carve((size_t)B_SZ * DALL * 2);
  bf16* h2    = (bf16*)carve((size_t)B_SZ * DALL * 2);
  float* pkT  = (float*)carve((size_t)PDIM * NSLOT * 4);
  float* mkT  = (float*)carve((size_t)MDIM * NSLOT * 4);
  bf16* fusedb = hpreb;  // alias: hpreb last read by ln_gelu

  keyt_kernel<<<dim3(3), 256, 0, stream>>>(pkey, mkey, pkT, mkT);
  all_conv<<<dim3(8352), 256, 0, stream>>>(pval, mval, pvb, mvb, pw, pwTb,
                                           w2, w2t, ps, mac, pkT, mkT, psb, att);
  precompute_direct<<<dim3(DALL / 256, KS2), 256, 0, stream>>>(w1, pvb, mvb, part);
  reduce_cvt<<<dim3(DALL * 128 / 1024), 256, 0, stream>>>(part, cvt);
  gemm_thin<<<dim3(DALL / 128, B_SZ / 128), 256, 0, stream>>>(att, cvt, hpreb, b1);
  ln_gelu_kernel<<<dim3(B_SZ), 256, 0, stream>>>(hpreb, lng1, lnb1, h2);
  gemm224<<<dim3(256), 512, 0, stream>>>(h2, w2t, fusedb, b2);
  pair_final<<<dim3(B_SZ / 128, NPAIR), 256, 0, stream>>>(
      psb, fusedb, pwTb, pb, plng, plnb, out);
}